// Round 1
// 171.803 us; speedup vs baseline: 1.0007x; 1.0007x over previous
//
#include <hip/hip_runtime.h>
#include <hip/hip_fp16.h>

#define HH 256
#define WW 256
#define KK 81
#define PLANE (HH * WW)
#define SLACK 10          // tile halo: rows [ho-10, ho+10], cols [xb, xb+83]
#define TR 21             // tile rows
#define TC 84             // tile cols (64-px strip + 4+SLACK halo each side)
#define TAB (TR * TC)     // 1764 cells per plane

// Pack [B,3,H,W] fp32 -> [B,H,W] ushort4 of fp16 (c0,c1,c2,0): one 8 B cell
// carries all 3 color groups for a pixel.
__global__ __launch_bounds__(256) void pack_kernel(const float* __restrict__ in,
                                                   ushort4* __restrict__ img) {
    int idx = blockIdx.x * 256 + threadIdx.x;  // b*PLANE + pix
    int b = idx >> 16;
    int pix = idx & 0xFFFF;
    const float* base = in + (size_t)b * 3 * PLANE + pix;
    _Float16 h0 = (_Float16)base[0];
    _Float16 h1 = (_Float16)base[PLANE];
    _Float16 h2 = (_Float16)base[2 * PLANE];
    ushort4 u;
    u.x = __builtin_bit_cast(unsigned short, h0);
    u.y = __builtin_bit_cast(unsigned short, h1);
    u.z = __builtin_bit_cast(unsigned short, h2);
    u.w = 0;
    img[idx] = u;
}

__device__ __forceinline__ void acc3(float w, unsigned int pa, unsigned int pb,
                                     float& ax, float& ay, float& az) {
    __half2 ha = __builtin_bit_cast(__half2, pa);
    __half2 hb = __builtin_bit_cast(__half2, pb);
    ax = fmaf(w, __low2float(ha), ax);   // v_fma_mix_f32 (lo)
    ay = fmaf(w, __high2float(ha), ay);  // v_fma_mix_f32 (hi)
    az = fmaf(w, __low2float(hb), az);
}

// Block = 64-pixel strip of one output row. 4 waves split the 81 taps
// (21/20/20/20) and LDS-reduce. Input tile staged ZERO-PADDED in LDS as ONE
// 8 B cell per pixel (uint2: lo = fp16x2 c0c1, hi = fp16 c2). The 4 bilinear
// corners are then 4 aligned ds_read_b64 at constant offsets {0,8,672,680}
// from a single base -> compiler merges into 2x ds_read2_b64 per tap
// (was 8x ds_read_b32). Tile row r == image row yb+r exactly (zeros outside
// the image), so unclamped index math is correct and out-of-image corners
// contribute 0 through the data (DCNv2 semantics).
__global__ __launch_bounds__(256, 8) void dcn_kernel(
    const ushort4* __restrict__ img,
    const float* __restrict__ offset,
    const float* __restrict__ mask,
    const float* __restrict__ weight,
    const float* __restrict__ bias,
    float* __restrict__ out) {
    __shared__ uint2 tile[TAB];       // 14112 B interleaved cells
    __shared__ float red[3][4][64];   // 3072 B
    __shared__ float wk[KK];

    const int t = threadIdx.x;
    if (t < KK) wk[t] = weight[t];

    const int b = blockIdx.y;
    const int pix0 = blockIdx.x * 64;
    const int ho = pix0 >> 8;                 // strip stays in one output row
    const int xb = (pix0 & 255) - SLACK;
    const int yb = ho - SLACK;
    const ushort4* ib = img + (size_t)b * PLANE;

    // stage tile: 1764 cells, zero outside the image, one ds_write_b64 each
    for (int i = 0; i < 7; ++i) {
        int cid = t + i * 256;
        if (cid < TAB) {
            int r = cid / TC;
            int c = cid - r * TC;
            int iy = yb + r;
            int ix = xb + c;
            unsigned int pa = 0, pb = 0;
            if (((unsigned)iy < (unsigned)HH) & ((unsigned)ix < (unsigned)WW)) {
                ushort4 u = ib[iy * WW + ix];
                pa = (unsigned int)u.x | ((unsigned int)u.y << 16);
                pb = (unsigned int)u.z;
            }
            tile[cid] = make_uint2(pa, pb);
        }
    }
    __syncthreads();

    const int w = t >> 6;
    const int lane = t & 63;
    const int wo = (pix0 & 255) + lane;
    const int pix = pix0 + lane;

    // k-range per wave: [0,21) [21,41) [41,61) [61,81)
    const int kbeg = w * 20 + (w ? 1 : 0);
    const int kend = kbeg + (w ? 20 : 21);
    int ky = kbeg / 9;
    int kx = kbeg - ky * 9;

    const float* op = offset + (size_t)b * 2 * KK * PLANE + (size_t)(2 * kbeg) * PLANE + pix;
    const float* mp = mask + (size_t)b * KK * PLANE + (size_t)kbeg * PLANE + pix;

    const float wof = (float)wo;
    float ax = 0.f, ay = 0.f, az = 0.f;

#pragma unroll 4
    for (int k = kbeg; k < kend; ++k) {
        float dy = op[0];
        float dx = op[PLANE];
        float m = mp[0] * wk[k];
        op += 2 * PLANE;
        mp += PLANE;

        float py = (float)(ho - 4 + ky) + dy;
        float px = wof + ((float)(kx - 4) + dx);
        float y0f = floorf(py), x0f = floorf(px);
        float wy = py - y0f, wx = px - x0f;
        int y0 = (int)y0f, x0 = (int)x0f;

        // unclamped tile coords: tile row r == image row yb+r (zero-padded)
        int r0 = y0 - yb;
        int c0 = x0 - xb;
        bool ok = ((unsigned)r0 < (TR - 1)) & ((unsigned)c0 < (TC - 1));

        float w1y = wy * m, w0y = m - w1y;      // a0*m, a1*m (validity via data)
        float w00 = w0y * (1.f - wx), w01 = w0y * wx;
        float w10 = w1y * (1.f - wx), w11 = w1y * wx;

        uint2 q00, q01, q10, q11;
        if (__builtin_expect(__all(ok), 1)) {
            const uint2* p = &tile[r0 * TC + c0];
            q00 = p[0];
            q01 = p[1];
            q10 = p[TC];
            q11 = p[TC + 1];
        } else {
            if (ok) {
                const uint2* p = &tile[r0 * TC + c0];
                q00 = p[0];
                q01 = p[1];
                q10 = p[TC];
                q11 = p[TC + 1];
            } else {
                // fully clamped + validity-masked global fallback
                int y1 = y0 + 1, x1 = x0 + 1;
                float va0 = ((unsigned)y0 < (unsigned)HH) ? 1.f : 0.f;
                float va1 = ((unsigned)y1 < (unsigned)HH) ? 1.f : 0.f;
                float vb0 = ((unsigned)x0 < (unsigned)WW) ? 1.f : 0.f;
                float vb1 = ((unsigned)x1 < (unsigned)WW) ? 1.f : 0.f;
                w00 *= va0 * vb0;
                w01 *= va0 * vb1;
                w10 *= va1 * vb0;
                w11 *= va1 * vb1;
                int y0c = min(max(y0, 0), HH - 1);
                int y1c = min(max(y1, 0), HH - 1);
                int x0c = min(max(x0, 0), WW - 1);
                int x1c = min(max(x1, 0), WW - 1);
                ushort4 g00 = ib[y0c * WW + x0c];
                ushort4 g01 = ib[y0c * WW + x1c];
                ushort4 g10 = ib[y1c * WW + x0c];
                ushort4 g11 = ib[y1c * WW + x1c];
                q00 = make_uint2((unsigned int)g00.x | ((unsigned int)g00.y << 16), g00.z);
                q01 = make_uint2((unsigned int)g01.x | ((unsigned int)g01.y << 16), g01.z);
                q10 = make_uint2((unsigned int)g10.x | ((unsigned int)g10.y << 16), g10.z);
                q11 = make_uint2((unsigned int)g11.x | ((unsigned int)g11.y << 16), g11.z);
            }
        }

        acc3(w00, q00.x, q00.y, ax, ay, az);
        acc3(w01, q01.x, q01.y, ax, ay, az);
        acc3(w10, q10.x, q10.y, ax, ay, az);
        acc3(w11, q11.x, q11.y, ax, ay, az);

        if (++kx == 9) {
            kx = 0;
            ++ky;
        }
    }

    red[0][w][lane] = ax;
    red[1][w][lane] = ay;
    red[2][w][lane] = az;
    __syncthreads();

    if (t < 192) {
        const int c = t >> 6;
        const int l = t & 63;
        float s = red[c][0][l] + red[c][1][l] + red[c][2][l] + red[c][3][l] + bias[0];
        out[(size_t)b * 3 * PLANE + (size_t)c * PLANE + pix0 + l] = s;
    }
}

extern "C" void kernel_launch(void* const* d_in, const int* in_sizes, int n_in,
                              void* d_out, int out_size, void* d_ws, size_t ws_size,
                              hipStream_t stream) {
    const float* input = (const float*)d_in[0];
    const float* offset = (const float*)d_in[1];
    const float* mask = (const float*)d_in[2];
    const float* weight = (const float*)d_in[3];
    const float* bias = (const float*)d_in[4];
    float* out = (float*)d_out;

    const int B = in_sizes[0] / (3 * PLANE);  // 2
    ushort4* img = (ushort4*)d_ws;            // 1 MB packed fp16 image

    pack_kernel<<<B * PLANE / 256, 256, 0, stream>>>(input, img);
    dim3 grid(PLANE / 64, B);
    dcn_kernel<<<grid, 256, 0, stream>>>(img, offset, mask, weight, bias, out);
}